// Round 1
// baseline (559.218 us; speedup 1.0000x reference)
//
#include <hip/hip_runtime.h>
#include <stdint.h>

#define NBOX 8000
#define NPAD 8192
#define NW   128   // 64-bit words per mask row (8192 bits)

// ---- workspace layout (bytes) ----
#define COUNT_OFF 0
#define KEYS_OFF  256                       // 8192 * 8 = 65536
#define U_OFF     (KEYS_OFF + NPAD * 8)     // 6 unsorted arrays
#define UARR(i)   (U_OFF + (size_t)(i) * NPAD * 4)   // bx,by,bw,bh,conf,cls
#define S_OFF     (U_OFF + 6 * NPAD * 4)
#define SIDX_OFF  S_OFF                      // int[8192]
#define SARR(i)   (S_OFF + NPAD * 4 + (size_t)(i) * NPAD * 4) // x1,y1,x2,y2,area,cls
#define KEEP_OFF  (S_OFF + 7 * NPAD * 4)     // 128 * 8 = 1KB
#define MASK_OFF  (size_t)524288             // 8192 * 128 * 8 = 8 MB
// total ~8.9 MB of ws

__device__ __forceinline__ float sigmoidf_(float x) {
    return 1.0f / (1.0f + expf(-x));
}

// ---------------- decode: 8000 boxes + key packing ----------------
__global__ __launch_bounds__(256) void decode_kernel(const float* __restrict__ x,
                                                     const float* __restrict__ anchors,
                                                     unsigned char* __restrict__ ws) {
    int n = blockIdx.x * 256 + threadIdx.x;
    if (n >= NPAD) return;
    unsigned long long* keys = (unsigned long long*)(ws + KEYS_OFF);
    if (n >= NBOX) {                       // pad keys sink to the end (conf bits = 0)
        keys[n] = (unsigned long long)(8191 - n);
        return;
    }
    int a   = n / 1600;
    int pos = n - a * 1600;
    int gy  = pos / 40;
    int gx  = pos - gy * 40;
    const float* p = x + (size_t)a * 25 * 1600 + pos;

    float tx   = sigmoidf_(p[0]);
    float ty   = sigmoidf_(p[1600]);
    float tw   = p[2 * 1600];
    float th   = p[3 * 1600];
    float conf = sigmoidf_(p[4 * 1600]);

    float best = -1.0f; int bi = 0;
    #pragma unroll
    for (int c = 0; c < 20; ++c) {          // first-max wins, matches jnp.argmax
        float v = sigmoidf_(p[(5 + c) * 1600]);
        if (v > best) { best = v; bi = c; }
    }

    float aw = anchors[a * 2 + 0];
    float ah = anchors[a * 2 + 1];
    float bx = (tx + (float)gx) * 8.0f;
    float by = (ty + (float)gy) * 8.0f;
    float bw = expf(tw) * aw * 8.0f;
    float bh = expf(th) * ah * 8.0f;

    ((float*)(ws + UARR(0)))[n] = bx;
    ((float*)(ws + UARR(1)))[n] = by;
    ((float*)(ws + UARR(2)))[n] = bw;
    ((float*)(ws + UARR(3)))[n] = bh;
    ((float*)(ws + UARR(4)))[n] = conf;
    ((float*)(ws + UARR(5)))[n] = (float)bi;

    unsigned int cb = __float_as_uint(conf);   // conf in (0,1): bits are monotonic
    keys[n] = ((unsigned long long)cb << 32) | (unsigned long long)(8191 - n);

    if (conf > 0.5f) atomicAdd((unsigned int*)(ws + COUNT_OFF), 1u);
}

// ---------------- single-block bitonic sort, descending ----------------
__global__ __launch_bounds__(1024) void sort_kernel(unsigned char* __restrict__ ws) {
    __shared__ unsigned long long s[NPAD];   // 64 KB
    unsigned long long* keys = (unsigned long long*)(ws + KEYS_OFF);
    int t = threadIdx.x;
    for (int i = t; i < NPAD; i += 1024) s[i] = keys[i];
    __syncthreads();
    for (int k = 2; k <= NPAD; k <<= 1) {
        for (int j = k >> 1; j > 0; j >>= 1) {
            for (int i = t; i < NPAD; i += 1024) {
                int l = i ^ j;
                if (l > i) {
                    unsigned long long a = s[i], b = s[l];
                    bool desc = ((i & k) == 0);
                    if ((a < b) == desc) { s[i] = b; s[l] = a; }
                }
            }
            __syncthreads();
        }
    }
    for (int i = t; i < NPAD; i += 1024) keys[i] = s[i];
}

// ---------------- gather sorted box geometry ----------------
__global__ __launch_bounds__(256) void gather_kernel(unsigned char* __restrict__ ws) {
#pragma clang fp contract(off)
    int r = blockIdx.x * 256 + threadIdx.x;
    if (r >= NPAD) return;
    unsigned long long key = ((unsigned long long*)(ws + KEYS_OFF))[r];
    int idx = 8191 - (int)(key & 0x1FFFull);
    ((int*)(ws + SIDX_OFF))[r] = idx;
    float* sx1 = (float*)(ws + SARR(0));
    float* sy1 = (float*)(ws + SARR(1));
    float* sx2 = (float*)(ws + SARR(2));
    float* sy2 = (float*)(ws + SARR(3));
    float* sar = (float*)(ws + SARR(4));
    float* scl = (float*)(ws + SARR(5));
    if (idx < NBOX) {
        float cx = ((float*)(ws + UARR(0)))[idx];
        float cy = ((float*)(ws + UARR(1)))[idx];
        float w  = ((float*)(ws + UARR(2)))[idx];
        float h  = ((float*)(ws + UARR(3)))[idx];
        float x1 = cx - w / 2.0f;
        float y1 = cy - h / 2.0f;
        float x2 = cx + w / 2.0f;
        float y2 = cy + h / 2.0f;
        sx1[r] = x1; sy1[r] = y1; sx2[r] = x2; sy2[r] = y2;
        sar[r] = fabsf((x2 - x1) * (y2 - y1));   // matches ref: recomputed from corners
        scl[r] = ((float*)(ws + UARR(5)))[idx];
    } else {
        sx1[r] = 0.f; sy1[r] = 0.f; sx2[r] = 0.f; sy2[r] = 0.f;
        sar[r] = 0.f; scl[r] = -1.0f;
    }
}

// ---------------- suppression bitmask: bit j of row i = (j>i, same cls, IoU>=0.5) ----------------
__global__ __launch_bounds__(256) void mask_kernel(unsigned char* __restrict__ ws) {
#pragma clang fp contract(off)
    int V = *(int*)(ws + COUNT_OFF);
    if ((int)(blockIdx.y * 256) >= V) return;      // uniform early-exit
    int i  = blockIdx.y * 256 + threadIdx.x;
    int w  = blockIdx.x;
    int j0 = w * 64;

    const float* sx1 = (const float*)(ws + SARR(0));
    const float* sy1 = (const float*)(ws + SARR(1));
    const float* sx2 = (const float*)(ws + SARR(2));
    const float* sy2 = (const float*)(ws + SARR(3));
    const float* sar = (const float*)(ws + SARR(4));
    const float* scl = (const float*)(ws + SARR(5));

    __shared__ float cx1[64], cy1[64], cx2[64], cy2[64], car[64], ccl[64];
    if (threadIdx.x < 64) {
        int j = j0 + threadIdx.x;
        cx1[threadIdx.x] = sx1[j]; cy1[threadIdx.x] = sy1[j];
        cx2[threadIdx.x] = sx2[j]; cy2[threadIdx.x] = sy2[j];
        car[threadIdx.x] = sar[j]; ccl[threadIdx.x] = scl[j];
    }
    __syncthreads();
    if (i >= V) return;

    unsigned long long word = 0;
    if (j0 + 64 > i + 1 && j0 < V) {
        float x1i = sx1[i], y1i = sy1[i], x2i = sx2[i], y2i = sy2[i];
        float ai = sar[i], ci = scl[i];
        for (int jj = 0; jj < 64; ++jj) {
            int j = j0 + jj;
            if (j <= i || j >= V) continue;
            if (ccl[jj] != ci) continue;
            float iw = fminf(x2i, cx2[jj]) - fmaxf(x1i, cx1[jj]);
            iw = fmaxf(iw, 0.0f);
            float ih = fminf(y2i, cy2[jj]) - fmaxf(y1i, cy1[jj]);
            ih = fmaxf(ih, 0.0f);
            float inter = iw * ih;
            float denom = ai + car[jj] - inter + 1e-6f;   // ((ai+aj)-inter)+eps, L-to-R
            if (inter / denom >= 0.5f) word |= (1ull << jj);
        }
    }
    ((unsigned long long*)(ws + MASK_OFF))[(size_t)i * NW + w] = word;
}

// ---------------- serial greedy scan: single wave, mask words live in registers ----------------
#define LOADC(b0, b1, B) { _Pragma("unroll") for (int k = 0; k < 16; ++k) { \
    size_t row = (size_t)((B) + k) * NW; \
    b0[k] = mask[row + lane]; b1[k] = mask[row + 64 + lane]; } }

#define PROCC(b0, b1, B) { _Pragma("unroll") for (int k = 0; k < 16; ++k) { \
    int i = (B) + k; \
    if (i < V) { \
        int wd = i >> 6; \
        unsigned long long sel = (wd < 64) ? r0 : r1; \
        unsigned long long bv = __shfl(sel, wd & 63, 64); \
        if (!((bv >> (i & 63)) & 1ull)) { r0 |= b0[k]; r1 |= b1[k]; } \
    } } }

__global__ __launch_bounds__(64) void scan_kernel(unsigned char* __restrict__ ws) {
    int lane = threadIdx.x;
    int V = *(int*)(ws + COUNT_OFF);
    const unsigned long long* mask = (const unsigned long long*)(ws + MASK_OFF);
    unsigned long long r0 = 0, r1 = 0;      // lane owns words lane and 64+lane
    unsigned long long A0[16], A1[16], B0[16], B1[16];

    if (V > 0) {
        int base = 0;
        LOADC(A0, A1, 0);
        while (base < V) {
            LOADC(B0, B1, base + 16);
            PROCC(A0, A1, base);
            base += 16;
            if (base >= V) break;
            LOADC(A0, A1, base + 16);
            PROCC(B0, B1, base);
            base += 16;
        }
    }
    unsigned long long* keepw = (unsigned long long*)(ws + KEEP_OFF);
    keepw[lane]      = ~r0;
    keepw[64 + lane] = ~r1;
}

// ---------------- write output: kept rows get box values, everything else zero ----------------
__global__ __launch_bounds__(256) void output_kernel(const unsigned char* __restrict__ ws,
                                                     float* __restrict__ out) {
    int r = blockIdx.x * 256 + threadIdx.x;
    if (r >= NBOX) return;
    int V = *(const int*)(ws + COUNT_OFF);
    const unsigned long long* keepw = (const unsigned long long*)(ws + KEEP_OFF);
    bool keep = (r < V) && ((keepw[r >> 6] >> (r & 63)) & 1ull);
    int idx = ((const int*)(ws + SIDX_OFF))[r];
    float o0 = 0.f, o1 = 0.f, o2 = 0.f, o3 = 0.f, o4 = 0.f, o5 = 0.f;
    if (keep && idx < NBOX) {
        o0 = ((const float*)(ws + UARR(0)))[idx];
        o1 = ((const float*)(ws + UARR(1)))[idx];
        o2 = ((const float*)(ws + UARR(2)))[idx];
        o3 = ((const float*)(ws + UARR(3)))[idx];
        o4 = ((const float*)(ws + UARR(4)))[idx];
        o5 = ((const float*)(ws + UARR(5)))[idx];
    }
    out[r * 6 + 0] = o0;
    out[r * 6 + 1] = o1;
    out[r * 6 + 2] = o2;
    out[r * 6 + 3] = o3;
    out[r * 6 + 4] = o4;
    out[r * 6 + 5] = o5;
}

extern "C" void kernel_launch(void* const* d_in, const int* in_sizes, int n_in,
                              void* d_out, int out_size, void* d_ws, size_t ws_size,
                              hipStream_t stream) {
    const float* x       = (const float*)d_in[0];
    const float* anchors = (const float*)d_in[1];
    float* out           = (float*)d_out;
    unsigned char* ws    = (unsigned char*)d_ws;

    hipMemsetAsync(ws + COUNT_OFF, 0, 256, stream);          // zero the valid-count
    decode_kernel<<<NPAD / 256, 256, 0, stream>>>(x, anchors, ws);
    sort_kernel<<<1, 1024, 0, stream>>>(ws);
    gather_kernel<<<NPAD / 256, 256, 0, stream>>>(ws);
    dim3 mgrid(NW, NPAD / 256);
    mask_kernel<<<mgrid, 256, 0, stream>>>(ws);
    scan_kernel<<<1, 64, 0, stream>>>(ws);
    output_kernel<<<NPAD / 256, 256, 0, stream>>>(ws, out);
}

// Round 2
// 497.235 us; speedup vs baseline: 1.1247x; 1.1247x over previous
//
#include <hip/hip_runtime.h>
#include <stdint.h>

#define NBOX 8000
#define NPAD 8192
#define NW   128   // 64-bit words per mask row (8192 bits)

// ---- workspace layout (bytes) ----
#define COUNT_OFF 0
#define KEYS_OFF  256                       // 8192 * 8 = 65536
#define U_OFF     (KEYS_OFF + NPAD * 8)     // 6 unsorted arrays
#define UARR(i)   (U_OFF + (size_t)(i) * NPAD * 4)   // bx,by,bw,bh,conf,cls
#define S_OFF     (U_OFF + 6 * NPAD * 4)
#define SIDX_OFF  S_OFF                      // int[8192]
#define SARR(i)   (S_OFF + NPAD * 4 + (size_t)(i) * NPAD * 4) // x1,y1,x2,y2,area,cls
#define KEEP_OFF  (S_OFF + 7 * NPAD * 4)     // 128 * 8 = 1KB
#define MASK_OFF  (size_t)524288             // 8192 * 128 * 8 = 8 MB
// total ~8.9 MB of ws

__device__ __forceinline__ float sigmoidf_(float x) {
    return 1.0f / (1.0f + expf(-x));
}

__device__ __forceinline__ unsigned long long readlane64(unsigned long long v, int l) {
    unsigned int lo = (unsigned int)__builtin_amdgcn_readlane((int)(unsigned int)(v & 0xffffffffull), l);
    unsigned int hi = (unsigned int)__builtin_amdgcn_readlane((int)(unsigned int)(v >> 32), l);
    return ((unsigned long long)hi << 32) | (unsigned long long)lo;
}

// ---------------- decode: 8000 boxes + key packing ----------------
__global__ __launch_bounds__(256) void decode_kernel(const float* __restrict__ x,
                                                     const float* __restrict__ anchors,
                                                     unsigned char* __restrict__ ws) {
    int n = blockIdx.x * 256 + threadIdx.x;
    if (n >= NPAD) return;
    unsigned long long* keys = (unsigned long long*)(ws + KEYS_OFF);
    if (n >= NBOX) {                       // pad keys sink to the end (conf bits = 0)
        keys[n] = (unsigned long long)(8191 - n);
        return;
    }
    int a   = n / 1600;
    int pos = n - a * 1600;
    int gy  = pos / 40;
    int gx  = pos - gy * 40;
    const float* p = x + (size_t)a * 25 * 1600 + pos;

    float tx   = sigmoidf_(p[0]);
    float ty   = sigmoidf_(p[1600]);
    float tw   = p[2 * 1600];
    float th   = p[3 * 1600];
    float conf = sigmoidf_(p[4 * 1600]);

    float best = -1.0f; int bi = 0;
    #pragma unroll
    for (int c = 0; c < 20; ++c) {          // first-max wins, matches jnp.argmax
        float v = sigmoidf_(p[(5 + c) * 1600]);
        if (v > best) { best = v; bi = c; }
    }

    float aw = anchors[a * 2 + 0];
    float ah = anchors[a * 2 + 1];
    float bx = (tx + (float)gx) * 8.0f;
    float by = (ty + (float)gy) * 8.0f;
    float bw = expf(tw) * aw * 8.0f;
    float bh = expf(th) * ah * 8.0f;

    ((float*)(ws + UARR(0)))[n] = bx;
    ((float*)(ws + UARR(1)))[n] = by;
    ((float*)(ws + UARR(2)))[n] = bw;
    ((float*)(ws + UARR(3)))[n] = bh;
    ((float*)(ws + UARR(4)))[n] = conf;
    ((float*)(ws + UARR(5)))[n] = (float)bi;

    unsigned int cb = __float_as_uint(conf);   // conf in (0,1): bits are monotonic
    keys[n] = ((unsigned long long)cb << 32) | (unsigned long long)(8191 - n);

    if (conf > 0.5f) atomicAdd((unsigned int*)(ws + COUNT_OFF), 1u);
}

// ---------------- single-block bitonic sort, descending ----------------
__global__ __launch_bounds__(1024) void sort_kernel(unsigned char* __restrict__ ws) {
    __shared__ unsigned long long s[NPAD];   // 64 KB
    unsigned long long* keys = (unsigned long long*)(ws + KEYS_OFF);
    int t = threadIdx.x;
    for (int i = t; i < NPAD; i += 1024) s[i] = keys[i];
    __syncthreads();
    for (int k = 2; k <= NPAD; k <<= 1) {
        for (int j = k >> 1; j > 0; j >>= 1) {
            for (int i = t; i < NPAD; i += 1024) {
                int l = i ^ j;
                if (l > i) {
                    unsigned long long a = s[i], b = s[l];
                    bool desc = ((i & k) == 0);
                    if ((a < b) == desc) { s[i] = b; s[l] = a; }
                }
            }
            __syncthreads();
        }
    }
    for (int i = t; i < NPAD; i += 1024) keys[i] = s[i];
}

// ---------------- gather sorted box geometry ----------------
__global__ __launch_bounds__(256) void gather_kernel(unsigned char* __restrict__ ws) {
#pragma clang fp contract(off)
    int r = blockIdx.x * 256 + threadIdx.x;
    if (r >= NPAD) return;
    unsigned long long key = ((unsigned long long*)(ws + KEYS_OFF))[r];
    int idx = 8191 - (int)(key & 0x1FFFull);
    ((int*)(ws + SIDX_OFF))[r] = idx;
    float* sx1 = (float*)(ws + SARR(0));
    float* sy1 = (float*)(ws + SARR(1));
    float* sx2 = (float*)(ws + SARR(2));
    float* sy2 = (float*)(ws + SARR(3));
    float* sar = (float*)(ws + SARR(4));
    float* scl = (float*)(ws + SARR(5));
    if (idx < NBOX) {
        float cx = ((float*)(ws + UARR(0)))[idx];
        float cy = ((float*)(ws + UARR(1)))[idx];
        float w  = ((float*)(ws + UARR(2)))[idx];
        float h  = ((float*)(ws + UARR(3)))[idx];
        float x1 = cx - w / 2.0f;
        float y1 = cy - h / 2.0f;
        float x2 = cx + w / 2.0f;
        float y2 = cy + h / 2.0f;
        sx1[r] = x1; sy1[r] = y1; sx2[r] = x2; sy2[r] = y2;
        sar[r] = fabsf((x2 - x1) * (y2 - y1));   // matches ref: recomputed from corners
        scl[r] = ((float*)(ws + UARR(5)))[idx];
    } else {
        sx1[r] = 0.f; sy1[r] = 0.f; sx2[r] = 0.f; sy2[r] = 0.f;
        sar[r] = 0.f; scl[r] = -1.0f;
    }
}

// ---------------- suppression bitmask: bit j of row i = (j>i, same cls, IoU>=0.5) ----------------
__global__ __launch_bounds__(256) void mask_kernel(unsigned char* __restrict__ ws) {
#pragma clang fp contract(off)
    int V = *(int*)(ws + COUNT_OFF);
    if ((int)(blockIdx.y * 256) >= V) return;      // uniform early-exit
    int i  = blockIdx.y * 256 + threadIdx.x;
    int w  = blockIdx.x;
    int j0 = w * 64;

    const float* sx1 = (const float*)(ws + SARR(0));
    const float* sy1 = (const float*)(ws + SARR(1));
    const float* sx2 = (const float*)(ws + SARR(2));
    const float* sy2 = (const float*)(ws + SARR(3));
    const float* sar = (const float*)(ws + SARR(4));
    const float* scl = (const float*)(ws + SARR(5));

    __shared__ float cx1[64], cy1[64], cx2[64], cy2[64], car[64], ccl[64];
    if (threadIdx.x < 64) {
        int j = j0 + threadIdx.x;
        cx1[threadIdx.x] = sx1[j]; cy1[threadIdx.x] = sy1[j];
        cx2[threadIdx.x] = sx2[j]; cy2[threadIdx.x] = sy2[j];
        car[threadIdx.x] = sar[j]; ccl[threadIdx.x] = scl[j];
    }
    __syncthreads();
    if (i >= V) return;

    unsigned long long word = 0;
    if (j0 + 64 > i + 1 && j0 < V) {
        float x1i = sx1[i], y1i = sy1[i], x2i = sx2[i], y2i = sy2[i];
        float ai = sar[i], ci = scl[i];
        for (int jj = 0; jj < 64; ++jj) {
            int j = j0 + jj;
            if (j <= i || j >= V) continue;
            if (ccl[jj] != ci) continue;
            float iw = fminf(x2i, cx2[jj]) - fmaxf(x1i, cx1[jj]);
            iw = fmaxf(iw, 0.0f);
            float ih = fminf(y2i, cy2[jj]) - fmaxf(y1i, cy1[jj]);
            ih = fmaxf(ih, 0.0f);
            float inter = iw * ih;
            float denom = ai + car[jj] - inter + 1e-6f;   // ((ai+aj)-inter)+eps, L-to-R
            if (inter / denom >= 0.5f) word |= (1ull << jj);
        }
    }
    ((unsigned long long*)(ws + MASK_OFF))[(size_t)i * NW + w] = word;
}

// ---------------- greedy scan: scalar-unit chunk resolve, 64 rows at a time ----------------
// Fast path (V <= 4096): lane owns mask word `lane`; per chunk of 64 rows:
//   aw   = word c of running suppression vector (ONE readlane)
//   dA   = word c of each chunk-row's mask (one 8B load/lane) -> intra-chunk 64x64 block
//   resolve greedy over set-bits of `alive` on the SCALAR unit (ctz loop, 2 readlanes/step)
//   OR surviving rows' full mask rows into r0 (uniform-branch v_or, unrolled)
// Loads are double-buffered one chunk ahead in register arrays (single wave -> VGPRs free).

#define LOAD_CH(ARR, DG, C) do {                                             \
    int c_ = (C);                                                            \
    size_t rb_ = (size_t)(c_ << 6) * NW;                                     \
    bool ld_ = (lane >= c_) && (lane < maxw);                                \
    _Pragma("unroll") for (int k_ = 0; k_ < 64; ++k_) {                      \
        ARR[k_] = ld_ ? mask[rb_ + (size_t)k_ * NW + lane] : 0ull;           \
    }                                                                        \
    DG = mask[rb_ + (size_t)lane * NW + c_];                                 \
} while (0)

#define PROC_CH(ARR, DG, C) do {                                             \
    int c_ = (C);                                                            \
    unsigned long long aw_ = readlane64(r0, c_);                             \
    int rem_ = V - (c_ << 6);                                                \
    unsigned long long tail_ = (rem_ >= 64) ? ~0ull : ((1ull << rem_) - 1ull); \
    unsigned long long alive_ = ~aw_ & tail_;                                \
    unsigned long long work_ = alive_;                                       \
    while (work_) {                                                          \
        int k_ = __builtin_ctzll(work_);                                     \
        work_ &= work_ - 1ull;                                               \
        unsigned long long dk_ = readlane64(DG, k_);                         \
        alive_ &= ~dk_;                                                      \
        work_ &= ~dk_;                                                       \
    }                                                                        \
    _Pragma("unroll") for (int k_ = 0; k_ < 64; ++k_) {                      \
        if ((alive_ >> k_) & 1ull) r0 |= ARR[k_];                            \
    }                                                                        \
} while (0)

__global__ __launch_bounds__(64, 1) void scan_kernel(unsigned char* __restrict__ ws) {
    int lane = threadIdx.x;
    int V = *(int*)(ws + COUNT_OFF);
    if (V > NPAD) V = NPAD;
    const unsigned long long* mask = (const unsigned long long*)(ws + MASK_OFF);
    unsigned long long* keepw = (unsigned long long*)(ws + KEEP_OFF);

    unsigned long long r0 = 0, r1 = 0;
    int nch  = (V + 63) >> 6;     // chunks of 64 rows
    int maxw = nch;               // only words [0, maxw) can be non-zero

    if (V > 0) {
        if (maxw <= 64) {
            // ---- fast path: word index == lane, double-buffered register arrays ----
            unsigned long long A[64], B[64], dA, dB;
            LOAD_CH(A, dA, 0);
            for (int c = 0; c < nch; c += 2) {
                if (c + 1 < nch) LOAD_CH(B, dB, c + 1);
                PROC_CH(A, dA, c);
                if (c + 1 >= nch) break;
                if (c + 2 < nch) LOAD_CH(A, dA, c + 2);
                PROC_CH(B, dB, c + 1);
            }
        } else {
            // ---- slow fallback (V > 4096): direct loads, lane owns words lane & 64+lane ----
            for (int c = 0; c < nch; ++c) {
                unsigned long long rs = (c < 64) ? r0 : r1;
                unsigned long long aw = readlane64(rs, c & 63);
                int rem = V - (c << 6);
                unsigned long long tail = (rem >= 64) ? ~0ull : ((1ull << rem) - 1ull);
                unsigned long long alive = ~aw & tail;
                unsigned long long d = mask[((size_t)(c << 6) + lane) * NW + c];
                unsigned long long work = alive;
                while (work) {
                    int k = __builtin_ctzll(work);
                    work &= work - 1ull;
                    unsigned long long dk = readlane64(d, k);
                    alive &= ~dk;
                    work &= ~dk;
                }
                unsigned long long w2 = alive;
                while (w2) {
                    int k = __builtin_ctzll(w2);
                    w2 &= w2 - 1ull;
                    size_t row = ((size_t)(c << 6) + k) * NW;
                    if (lane < maxw)      r0 |= mask[row + lane];
                    if (64 + lane < maxw) r1 |= mask[row + 64 + lane];
                }
            }
        }
    }
    keepw[lane]      = ~r0;
    keepw[64 + lane] = ~r1;
}

// ---------------- write output: kept rows get box values, everything else zero ----------------
__global__ __launch_bounds__(256) void output_kernel(const unsigned char* __restrict__ ws,
                                                     float* __restrict__ out) {
    int r = blockIdx.x * 256 + threadIdx.x;
    if (r >= NBOX) return;
    int V = *(const int*)(ws + COUNT_OFF);
    const unsigned long long* keepw = (const unsigned long long*)(ws + KEEP_OFF);
    bool keep = (r < V) && ((keepw[r >> 6] >> (r & 63)) & 1ull);
    int idx = ((const int*)(ws + SIDX_OFF))[r];
    float o0 = 0.f, o1 = 0.f, o2 = 0.f, o3 = 0.f, o4 = 0.f, o5 = 0.f;
    if (keep && idx < NBOX) {
        o0 = ((const float*)(ws + UARR(0)))[idx];
        o1 = ((const float*)(ws + UARR(1)))[idx];
        o2 = ((const float*)(ws + UARR(2)))[idx];
        o3 = ((const float*)(ws + UARR(3)))[idx];
        o4 = ((const float*)(ws + UARR(4)))[idx];
        o5 = ((const float*)(ws + UARR(5)))[idx];
    }
    out[r * 6 + 0] = o0;
    out[r * 6 + 1] = o1;
    out[r * 6 + 2] = o2;
    out[r * 6 + 3] = o3;
    out[r * 6 + 4] = o4;
    out[r * 6 + 5] = o5;
}

extern "C" void kernel_launch(void* const* d_in, const int* in_sizes, int n_in,
                              void* d_out, int out_size, void* d_ws, size_t ws_size,
                              hipStream_t stream) {
    const float* x       = (const float*)d_in[0];
    const float* anchors = (const float*)d_in[1];
    float* out           = (float*)d_out;
    unsigned char* ws    = (unsigned char*)d_ws;

    hipMemsetAsync(ws + COUNT_OFF, 0, 256, stream);          // zero the valid-count
    decode_kernel<<<NPAD / 256, 256, 0, stream>>>(x, anchors, ws);
    sort_kernel<<<1, 1024, 0, stream>>>(ws);
    gather_kernel<<<NPAD / 256, 256, 0, stream>>>(ws);
    dim3 mgrid(NW, NPAD / 256);
    mask_kernel<<<mgrid, 256, 0, stream>>>(ws);
    scan_kernel<<<1, 64, 0, stream>>>(ws);
    output_kernel<<<NPAD / 256, 256, 0, stream>>>(ws, out);
}

// Round 3
// 199.054 us; speedup vs baseline: 2.8094x; 2.4980x over previous
//
#include <hip/hip_runtime.h>
#include <stdint.h>

#define NBOX 8000
#define NPAD 8192
#define NW   128   // 64-bit words per mask row (8192 bits)

// ---- workspace layout (bytes) ----
#define COUNT_OFF 0
#define ROWNZ_OFF 128                        // 128 * 8 = 1 KB  (zeroed by memset)
#define VKEYS_OFF 0x1000                     // 8192 * 8 = 64 KB (compacted valid keys)
#define SKEYS_OFF 0x11000                    // 8192 * 8 = 64 KB (rank-sorted keys)
#define U_OFF     0x21000                    // 6 unsorted arrays
#define UARR(i)   (U_OFF + (size_t)(i) * NPAD * 4)   // bx,by,bw,bh,conf,cls
#define SIDX_OFF  0x51000                    // int[8192]
#define SARR(i)   (0x59000 + (size_t)(i) * NPAD * 4) // x1,y1,x2,y2,area,cls
#define DIAG_OFF  0x89000                    // 8192 * 8 = 64 KB (diag block words)
#define KEEP_OFF  0x99000                    // 128 * 8 = 1 KB
#define MASK_OFF  (size_t)0xA0000            // rows < V only: typical ~4 MB touched

__device__ __forceinline__ float sigmoidf_(float x) {
    return 1.0f / (1.0f + expf(-x));
}

__device__ __forceinline__ unsigned long long readlane64(unsigned long long v, int l) {
    unsigned int lo = (unsigned int)__builtin_amdgcn_readlane((int)(unsigned int)(v & 0xffffffffull), l);
    unsigned int hi = (unsigned int)__builtin_amdgcn_readlane((int)(unsigned int)(v >> 32), l);
    return ((unsigned long long)hi << 32) | (unsigned long long)lo;
}

// ---------------- decode: 8000 boxes, compact valid (conf>0.5) keys ----------------
__global__ __launch_bounds__(256) void decode_kernel(const float* __restrict__ x,
                                                     const float* __restrict__ anchors,
                                                     unsigned char* __restrict__ ws) {
    int n = blockIdx.x * 256 + threadIdx.x;
    if (n >= NBOX) return;
    int a   = n / 1600;
    int pos = n - a * 1600;
    int gy  = pos / 40;
    int gx  = pos - gy * 40;
    const float* p = x + (size_t)a * 25 * 1600 + pos;

    float tx   = sigmoidf_(p[0]);
    float ty   = sigmoidf_(p[1600]);
    float tw   = p[2 * 1600];
    float th   = p[3 * 1600];
    float conf = sigmoidf_(p[4 * 1600]);

    float best = -1.0f; int bi = 0;
    #pragma unroll
    for (int c = 0; c < 20; ++c) {          // first-max wins, matches jnp.argmax
        float v = sigmoidf_(p[(5 + c) * 1600]);
        if (v > best) { best = v; bi = c; }
    }

    float aw = anchors[a * 2 + 0];
    float ah = anchors[a * 2 + 1];
    float bx = (tx + (float)gx) * 8.0f;
    float by = (ty + (float)gy) * 8.0f;
    float bw = expf(tw) * aw * 8.0f;
    float bh = expf(th) * ah * 8.0f;

    ((float*)(ws + UARR(0)))[n] = bx;
    ((float*)(ws + UARR(1)))[n] = by;
    ((float*)(ws + UARR(2)))[n] = bw;
    ((float*)(ws + UARR(3)))[n] = bh;
    ((float*)(ws + UARR(4)))[n] = conf;
    ((float*)(ws + UARR(5)))[n] = (float)bi;

    if (conf > 0.5f) {                       // strict >, matches ref
        unsigned int cb = __float_as_uint(conf);   // conf in (0,1): bits monotonic
        unsigned long long key = ((unsigned long long)cb << 32) | (unsigned long long)(8191 - n);
        unsigned int slot = atomicAdd((unsigned int*)(ws + COUNT_OFF), 1u);
        ((unsigned long long*)(ws + VKEYS_OFF))[slot] = key;
    }
}

// ---------------- brute-force rank (replaces sort): rank = #{keys greater} ----------------
// Keys are unique (idx tiebreak) so ranks are a permutation; descending order ==
// stable-descending by conf with original-index tiebreak, matching jnp.argsort(-conf).
__global__ __launch_bounds__(256) void rank_kernel(unsigned char* __restrict__ ws) {
    __shared__ unsigned long long tile[256];
    int V = *(const int*)(ws + COUNT_OFF);
    if (V > NPAD) V = NPAD;
    if ((int)(blockIdx.x << 8) >= V) return;       // uniform whole-block exit
    int i = blockIdx.x * 256 + threadIdx.x;
    const unsigned long long* vk = (const unsigned long long*)(ws + VKEYS_OFF);
    unsigned long long ki = (i < V) ? vk[i] : 0ull;
    int cnt = 0;
    int ntiles = (V + 255) >> 8;
    for (int tb = 0; tb < ntiles; ++tb) {
        int j = (tb << 8) + threadIdx.x;
        tile[threadIdx.x] = (j < V) ? vk[j] : 0ull;
        __syncthreads();
        int lim = V - (tb << 8);
        if (lim >= 256) {
            #pragma unroll 8
            for (int jj = 0; jj < 256; ++jj) cnt += (tile[jj] > ki) ? 1 : 0;
        } else {
            for (int jj = 0; jj < lim; ++jj) cnt += (tile[jj] > ki) ? 1 : 0;
        }
        __syncthreads();
    }
    if (i < V) ((unsigned long long*)(ws + SKEYS_OFF))[cnt] = ki;
}

// ---------------- gather sorted box geometry for ranks < V ----------------
__global__ __launch_bounds__(256) void gather_kernel(unsigned char* __restrict__ ws) {
#pragma clang fp contract(off)
    int r = blockIdx.x * 256 + threadIdx.x;
    if (r >= NPAD) return;
    int V = *(const int*)(ws + COUNT_OFF);
    if (V > NPAD) V = NPAD;
    float* sx1 = (float*)(ws + SARR(0));
    float* sy1 = (float*)(ws + SARR(1));
    float* sx2 = (float*)(ws + SARR(2));
    float* sy2 = (float*)(ws + SARR(3));
    float* sar = (float*)(ws + SARR(4));
    float* scl = (float*)(ws + SARR(5));
    if (r < V) {
        unsigned long long key = ((const unsigned long long*)(ws + SKEYS_OFF))[r];
        int idx = 8191 - (int)(key & 0x1FFFull);
        ((int*)(ws + SIDX_OFF))[r] = idx;
        float cx = ((float*)(ws + UARR(0)))[idx];
        float cy = ((float*)(ws + UARR(1)))[idx];
        float w  = ((float*)(ws + UARR(2)))[idx];
        float h  = ((float*)(ws + UARR(3)))[idx];
        float x1 = cx - w / 2.0f;
        float y1 = cy - h / 2.0f;
        float x2 = cx + w / 2.0f;
        float y2 = cy + h / 2.0f;
        sx1[r] = x1; sy1[r] = y1; sx2[r] = x2; sy2[r] = y2;
        sar[r] = fabsf((x2 - x1) * (y2 - y1));   // ref: recomputed from corners
        scl[r] = ((float*)(ws + UARR(5)))[idx];
    } else {
        ((int*)(ws + SIDX_OFF))[r] = -1;
        sx1[r] = 0.f; sy1[r] = 0.f; sx2[r] = 0.f; sy2[r] = 0.f;
        sar[r] = 0.f; scl[r] = -1.0f;
    }
}

// ---------------- suppression bitmask + diag + row-nonzero summary ----------------
__global__ __launch_bounds__(256) void mask_kernel(unsigned char* __restrict__ ws) {
#pragma clang fp contract(off)
    int V = *(int*)(ws + COUNT_OFF);
    if (V > NPAD) V = NPAD;
    if ((int)(blockIdx.y * 256) >= V) return;      // uniform early-exit
    int w  = blockIdx.x;
    int j0 = w * 64;
    if (j0 >= V) return;                           // uniform: word entirely past V
    int i  = blockIdx.y * 256 + threadIdx.x;

    const float* sx1 = (const float*)(ws + SARR(0));
    const float* sy1 = (const float*)(ws + SARR(1));
    const float* sx2 = (const float*)(ws + SARR(2));
    const float* sy2 = (const float*)(ws + SARR(3));
    const float* sar = (const float*)(ws + SARR(4));
    const float* scl = (const float*)(ws + SARR(5));

    __shared__ float cx1[64], cy1[64], cx2[64], cy2[64], car[64], ccl[64];
    if (threadIdx.x < 64) {
        int j = j0 + threadIdx.x;
        cx1[threadIdx.x] = sx1[j]; cy1[threadIdx.x] = sy1[j];
        cx2[threadIdx.x] = sx2[j]; cy2[threadIdx.x] = sy2[j];
        car[threadIdx.x] = sar[j]; ccl[threadIdx.x] = scl[j];
    }
    __syncthreads();
    if (i >= V) return;

    unsigned long long word = 0;
    if (j0 + 64 > i + 1) {
        float x1i = sx1[i], y1i = sy1[i], x2i = sx2[i], y2i = sy2[i];
        float ai = sar[i], ci = scl[i];
        for (int jj = 0; jj < 64; ++jj) {
            int j = j0 + jj;
            if (j <= i || j >= V) continue;
            if (ccl[jj] != ci) continue;
            float iw = fminf(x2i, cx2[jj]) - fmaxf(x1i, cx1[jj]);
            iw = fmaxf(iw, 0.0f);
            float ih = fminf(y2i, cy2[jj]) - fmaxf(y1i, cy1[jj]);
            ih = fmaxf(ih, 0.0f);
            float inter = iw * ih;
            float denom = ai + car[jj] - inter + 1e-6f;   // ((ai+aj)-inter)+eps, L-to-R
            if (inter / denom >= 0.5f) word |= (1ull << jj);
        }
    }
    ((unsigned long long*)(ws + MASK_OFF))[(size_t)i * NW + w] = word;
    if (w == (i >> 6))
        ((unsigned long long*)(ws + DIAG_OFF))[i] = word;   // diag block word
    if (word)
        atomicOr((unsigned long long*)(ws + ROWNZ_OFF) + (i >> 6), 1ull << (i & 63));
}

// ---------------- greedy scan: scalar resolve + sparse forward-OR ----------------
// Lane L owns suppression words L (r0) and 64+L (r1). Per 64-row chunk c:
//   aw    = word c of running suppression (one readlane64)
//   d     = diag words of chunk rows (coalesced 512B load, prefetched)
//   dnz   = ballot(d!=0): only rows that suppress within-chunk enter the scalar loop
//   alive = resolved greedily on the scalar unit (ctz over set bits)
//   fwd   = alive & rownz[c]: only rows with ANY nonzero mask word get their
//           512B coalesced mask row OR-ed into r0/r1 (4-wide batched for MLP)
__global__ __launch_bounds__(64, 1) void scan_kernel(unsigned char* __restrict__ ws) {
    int lane = threadIdx.x;
    int V = *(const int*)(ws + COUNT_OFF);
    if (V > NPAD) V = NPAD;
    const unsigned long long* mask = (const unsigned long long*)(ws + MASK_OFF);
    const unsigned long long* diag = (const unsigned long long*)(ws + DIAG_OFF);
    unsigned long long* keepw = (unsigned long long*)(ws + KEEP_OFF);

    unsigned long long rz_all = ((const unsigned long long*)(ws + ROWNZ_OFF))[lane];
    unsigned long long r0 = 0, r1 = 0;
    int nch  = (V + 63) >> 6;
    int maxw = nch;

    unsigned long long d = (nch > 0) ? diag[lane] : 0ull;
    for (int c = 0; c < nch; ++c) {
        unsigned long long dn = 0;
        if (c + 1 < nch) dn = diag[((c + 1) << 6) + lane];   // prefetch next diag

        unsigned long long rs = (c < 64) ? r0 : r1;
        unsigned long long aw = readlane64(rs, c & 63);
        int rem = V - (c << 6);
        unsigned long long tail = (rem >= 64) ? ~0ull : ((1ull << rem) - 1ull);
        unsigned long long alive = ~aw & tail;

        unsigned long long dnz = __ballot(d != 0ull);
        unsigned long long work = alive & dnz;
        while (work) {
            int k = __builtin_ctzll(work);
            work &= work - 1ull;
            unsigned long long dk = readlane64(d, k);
            alive &= ~dk;
            work &= ~dk;
        }

        int base = c << 6;
        unsigned long long fwd = alive & readlane64(rz_all, c);
        while (fwd) {
            int k0 = __builtin_ctzll(fwd); fwd &= fwd - 1ull;
            int k1 = -1, k2 = -1, k3 = -1;
            if (fwd) { k1 = __builtin_ctzll(fwd); fwd &= fwd - 1ull; }
            if (fwd) { k2 = __builtin_ctzll(fwd); fwd &= fwd - 1ull; }
            if (fwd) { k3 = __builtin_ctzll(fwd); fwd &= fwd - 1ull; }
            unsigned long long v0 = mask[(size_t)(base + k0) * NW + lane];
            unsigned long long v1 = 0, v2 = 0, v3 = 0;
            if (k1 >= 0) v1 = mask[(size_t)(base + k1) * NW + lane];
            if (k2 >= 0) v2 = mask[(size_t)(base + k2) * NW + lane];
            if (k3 >= 0) v3 = mask[(size_t)(base + k3) * NW + lane];
            r0 |= v0 | v1 | v2 | v3;
            if (maxw > 64) {
                unsigned long long w0 = mask[(size_t)(base + k0) * NW + 64 + lane];
                unsigned long long w1 = 0, w2 = 0, w3 = 0;
                if (k1 >= 0) w1 = mask[(size_t)(base + k1) * NW + 64 + lane];
                if (k2 >= 0) w2 = mask[(size_t)(base + k2) * NW + 64 + lane];
                if (k3 >= 0) w3 = mask[(size_t)(base + k3) * NW + 64 + lane];
                r1 |= w0 | w1 | w2 | w3;
            }
        }
        d = dn;
    }
    keepw[lane]      = ~r0;
    keepw[64 + lane] = ~r1;
}

// ---------------- write output: kept ranks get box values, everything else zero ----------------
__global__ __launch_bounds__(256) void output_kernel(const unsigned char* __restrict__ ws,
                                                     float* __restrict__ out) {
    int r = blockIdx.x * 256 + threadIdx.x;
    if (r >= NBOX) return;
    int V = *(const int*)(ws + COUNT_OFF);
    if (V > NPAD) V = NPAD;
    const unsigned long long* keepw = (const unsigned long long*)(ws + KEEP_OFF);
    bool keep = (r < V) && ((keepw[r >> 6] >> (r & 63)) & 1ull);
    float o0 = 0.f, o1 = 0.f, o2 = 0.f, o3 = 0.f, o4 = 0.f, o5 = 0.f;
    if (keep) {
        int idx = ((const int*)(ws + SIDX_OFF))[r];
        if (idx >= 0 && idx < NBOX) {
            o0 = ((const float*)(ws + UARR(0)))[idx];
            o1 = ((const float*)(ws + UARR(1)))[idx];
            o2 = ((const float*)(ws + UARR(2)))[idx];
            o3 = ((const float*)(ws + UARR(3)))[idx];
            o4 = ((const float*)(ws + UARR(4)))[idx];
            o5 = ((const float*)(ws + UARR(5)))[idx];
        }
    }
    out[r * 6 + 0] = o0;
    out[r * 6 + 1] = o1;
    out[r * 6 + 2] = o2;
    out[r * 6 + 3] = o3;
    out[r * 6 + 4] = o4;
    out[r * 6 + 5] = o5;
}

extern "C" void kernel_launch(void* const* d_in, const int* in_sizes, int n_in,
                              void* d_out, int out_size, void* d_ws, size_t ws_size,
                              hipStream_t stream) {
    const float* x       = (const float*)d_in[0];
    const float* anchors = (const float*)d_in[1];
    float* out           = (float*)d_out;
    unsigned char* ws    = (unsigned char*)d_ws;

    hipMemsetAsync(ws, 0, 2048, stream);           // zero count + rownz
    decode_kernel<<<(NBOX + 255) / 256, 256, 0, stream>>>(x, anchors, ws);
    rank_kernel<<<NPAD / 256, 256, 0, stream>>>(ws);
    gather_kernel<<<NPAD / 256, 256, 0, stream>>>(ws);
    dim3 mgrid(NW, NPAD / 256);
    mask_kernel<<<mgrid, 256, 0, stream>>>(ws);
    scan_kernel<<<1, 64, 0, stream>>>(ws);
    output_kernel<<<(NBOX + 255) / 256, 256, 0, stream>>>(ws, out);
}

// Round 4
// 159.899 us; speedup vs baseline: 3.4973x; 1.2449x over previous
//
#include <hip/hip_runtime.h>
#include <stdint.h>

#define NBOX 8000
#define NPAD 8192
#define NW   128   // 64-bit words per mask row (8192 bits)

// ---- workspace layout (bytes) ----
#define COUNT_OFF 0
#define ROWNZ_OFF 128                        // 128 * 8 = 1 KB
#define RANK_OFF  0x800                      // 8192 * 4 = 32 KB (zeroed by memset)
#define VKEYS_OFF 0x9000                     // 8192 * 8 = 64 KB (compacted valid keys)
#define U_OFF     0x20000                    // 6 unsorted arrays
#define UARR(i)   (U_OFF + (size_t)(i) * NPAD * 4)   // bx,by,bw,bh,conf,cls
#define SIDX_OFF  0x50000                    // int[8192]
#define SARR(i)   (0x58000 + (size_t)(i) * NPAD * 4) // x1,y1,x2,y2,area,cls
#define DIAG_OFF  0x88000                    // 8192 * 8 = 64 KB (diag block words)
#define KEEP_OFF  0x98000                    // 128 * 8 = 1 KB
#define MASK_OFF  (size_t)0xA0000            // 8 MB region; rows < V only touched

__device__ __forceinline__ float sigmoidf_(float x) {
    return 1.0f / (1.0f + expf(-x));
}

__device__ __forceinline__ unsigned long long readlane64(unsigned long long v, int l) {
    unsigned int lo = (unsigned int)__builtin_amdgcn_readlane((int)(unsigned int)(v & 0xffffffffull), l);
    unsigned int hi = (unsigned int)__builtin_amdgcn_readlane((int)(unsigned int)(v >> 32), l);
    return ((unsigned long long)hi << 32) | (unsigned long long)lo;
}

// ---------------- decode: 8000 boxes, compact valid (conf>0.5) keys ----------------
__global__ __launch_bounds__(256) void decode_kernel(const float* __restrict__ x,
                                                     const float* __restrict__ anchors,
                                                     unsigned char* __restrict__ ws) {
    int n = blockIdx.x * 256 + threadIdx.x;
    if (n >= NBOX) return;
    int a   = n / 1600;
    int pos = n - a * 1600;
    int gy  = pos / 40;
    int gx  = pos - gy * 40;
    const float* p = x + (size_t)a * 25 * 1600 + pos;

    float tx   = sigmoidf_(p[0]);
    float ty   = sigmoidf_(p[1600]);
    float tw   = p[2 * 1600];
    float th   = p[3 * 1600];
    float conf = sigmoidf_(p[4 * 1600]);

    float best = -1.0f; int bi = 0;
    #pragma unroll
    for (int c = 0; c < 20; ++c) {          // first-max wins, matches jnp.argmax
        float v = sigmoidf_(p[(5 + c) * 1600]);
        if (v > best) { best = v; bi = c; }
    }

    float aw = anchors[a * 2 + 0];
    float ah = anchors[a * 2 + 1];
    float bx = (tx + (float)gx) * 8.0f;
    float by = (ty + (float)gy) * 8.0f;
    float bw = expf(tw) * aw * 8.0f;
    float bh = expf(th) * ah * 8.0f;

    ((float*)(ws + UARR(0)))[n] = bx;
    ((float*)(ws + UARR(1)))[n] = by;
    ((float*)(ws + UARR(2)))[n] = bw;
    ((float*)(ws + UARR(3)))[n] = bh;
    ((float*)(ws + UARR(4)))[n] = conf;
    ((float*)(ws + UARR(5)))[n] = (float)bi;

    if (conf > 0.5f) {                       // strict >, matches ref
        unsigned int cb = __float_as_uint(conf);   // conf in (0,1): bits monotonic
        unsigned long long key = ((unsigned long long)cb << 32) | (unsigned long long)(8191 - n);
        unsigned int slot = atomicAdd((unsigned int*)(ws + COUNT_OFF), 1u);
        ((unsigned long long*)(ws + VKEYS_OFF))[slot] = key;
    }
}

// ---------------- 2D brute-force rank: rank[i] += #{keys in j-tile greater} ----------------
// Keys unique (idx tiebreak) -> ranks are a permutation; descending keys ==
// stable-descending conf with original-index tiebreak (matches jnp.argsort(-conf)).
__global__ __launch_bounds__(256) void rank_kernel(unsigned char* __restrict__ ws) {
    __shared__ unsigned long long tile[256];
    int V = *(const int*)(ws + COUNT_OFF);
    if (V > NPAD) V = NPAD;
    int i0 = blockIdx.y << 8;
    int j0 = blockIdx.x << 8;
    if (i0 >= V || j0 >= V) return;                 // uniform whole-block exit
    const unsigned long long* vk = (const unsigned long long*)(ws + VKEYS_OFF);
    int i = i0 + threadIdx.x;
    unsigned long long ki = (i < V) ? vk[i] : ~0ull;
    int j = j0 + threadIdx.x;
    tile[threadIdx.x] = (j < V) ? vk[j] : 0ull;     // pad 0 never counts (keys > 0)
    __syncthreads();
    int cnt = 0;
    #pragma unroll 8
    for (int jj = 0; jj < 256; ++jj) cnt += (tile[jj] > ki) ? 1 : 0;
    if (i < V && cnt) atomicAdd((int*)(ws + RANK_OFF) + i, cnt);
}

// ---------------- scatter by rank + compute sorted geometry ----------------
__global__ __launch_bounds__(256) void scatter_kernel(unsigned char* __restrict__ ws) {
#pragma clang fp contract(off)
    int i = blockIdx.x * 256 + threadIdx.x;
    if (i >= NPAD) return;
    int V = *(const int*)(ws + COUNT_OFF);
    if (V > NPAD) V = NPAD;
    float* sx1 = (float*)(ws + SARR(0));
    float* sy1 = (float*)(ws + SARR(1));
    float* sx2 = (float*)(ws + SARR(2));
    float* sy2 = (float*)(ws + SARR(3));
    float* sar = (float*)(ws + SARR(4));
    float* scl = (float*)(ws + SARR(5));
    if (i < V) {
        int r = ((const int*)(ws + RANK_OFF))[i];
        unsigned long long key = ((const unsigned long long*)(ws + VKEYS_OFF))[i];
        int idx = 8191 - (int)(key & 0x1FFFull);
        ((int*)(ws + SIDX_OFF))[r] = idx;
        float cx = ((float*)(ws + UARR(0)))[idx];
        float cy = ((float*)(ws + UARR(1)))[idx];
        float w  = ((float*)(ws + UARR(2)))[idx];
        float h  = ((float*)(ws + UARR(3)))[idx];
        float x1 = cx - w / 2.0f;
        float y1 = cy - h / 2.0f;
        float x2 = cx + w / 2.0f;
        float y2 = cy + h / 2.0f;
        sx1[r] = x1; sy1[r] = y1; sx2[r] = x2; sy2[r] = y2;
        sar[r] = fabsf((x2 - x1) * (y2 - y1));   // ref: recomputed from corners
        scl[r] = ((float*)(ws + UARR(5)))[idx];
    } else {
        int r = i;                                // ranks [V, NPAD) get defaults
        ((int*)(ws + SIDX_OFF))[r] = -1;
        sx1[r] = 0.f; sy1[r] = 0.f; sx2[r] = 0.f; sy2[r] = 0.f;
        sar[r] = 0.f; scl[r] = -1.0f;
    }
}

// ---------------- suppression bitmask + diag + row-nonzero summary ----------------
// Only words w with w*64+64 > i are ever read by scan (columns > row), so
// strictly-sub-diagonal blocks are skipped entirely (never written).
__global__ __launch_bounds__(256) void mask_kernel(unsigned char* __restrict__ ws) {
#pragma clang fp contract(off)
    int V = *(int*)(ws + COUNT_OFF);
    if (V > NPAD) V = NPAD;
    int i0 = blockIdx.y * 256;
    int w  = blockIdx.x;
    int j0 = w * 64;
    if (i0 >= V) return;                           // uniform early-exit
    if (j0 >= V) return;                           // word entirely past V
    if (j0 + 64 <= i0) return;                     // strictly sub-diagonal: all zero
    int i  = i0 + threadIdx.x;

    const float* sx1 = (const float*)(ws + SARR(0));
    const float* sy1 = (const float*)(ws + SARR(1));
    const float* sx2 = (const float*)(ws + SARR(2));
    const float* sy2 = (const float*)(ws + SARR(3));
    const float* sar = (const float*)(ws + SARR(4));
    const float* scl = (const float*)(ws + SARR(5));

    __shared__ float cx1[64], cy1[64], cx2[64], cy2[64], car[64], ccl[64];
    if (threadIdx.x < 64) {
        int j = j0 + threadIdx.x;
        cx1[threadIdx.x] = sx1[j]; cy1[threadIdx.x] = sy1[j];
        cx2[threadIdx.x] = sx2[j]; cy2[threadIdx.x] = sy2[j];
        car[threadIdx.x] = sar[j]; ccl[threadIdx.x] = scl[j];
    }
    __syncthreads();
    if (i >= V) return;

    unsigned long long word = 0;
    if (j0 + 64 > i + 1) {
        float x1i = sx1[i], y1i = sy1[i], x2i = sx2[i], y2i = sy2[i];
        float ai = sar[i], ci = scl[i];
        for (int jj = 0; jj < 64; ++jj) {
            int j = j0 + jj;
            if (j <= i || j >= V) continue;
            if (ccl[jj] != ci) continue;
            float iw = fminf(x2i, cx2[jj]) - fmaxf(x1i, cx1[jj]);
            iw = fmaxf(iw, 0.0f);
            float ih = fminf(y2i, cy2[jj]) - fmaxf(y1i, cy1[jj]);
            ih = fmaxf(ih, 0.0f);
            float inter = iw * ih;
            float denom = ai + car[jj] - inter + 1e-6f;   // ((ai+aj)-inter)+eps, L-to-R
            if (inter / denom >= 0.5f) word |= (1ull << jj);
        }
    }
    ((unsigned long long*)(ws + MASK_OFF))[(size_t)i * NW + w] = word;
    if (w == (i >> 6))
        ((unsigned long long*)(ws + DIAG_OFF))[i] = word;   // diag block word
    if (word)
        atomicOr((unsigned long long*)(ws + ROWNZ_OFF) + (i >> 6), 1ull << (i & 63));
}

// ---------------- greedy scan: 16-wave cooperative, LDS suppression vector ----------------
// supp lives in LDS (u32 pairs). Per 64-row chunk c:
//   wave 0: resolve intra-chunk aliveness (diag word + scalar ctz loop) -> salive
//   all waves: OR alive rows' mask rows (word = lane, words >= c only) into supp
//     via LDS atomicOr. Rows statically assigned k % 16 == wv, PREFETCHED one
//     chunk ahead (rownz-guided) so L2 latency hides behind the previous chunk.
__global__ __launch_bounds__(1024, 1) void scan_kernel(unsigned char* __restrict__ ws) {
    int tid  = threadIdx.x;
    int lane = tid & 63;
    int wv   = tid >> 6;                    // 0..15
    int V = *(const int*)(ws + COUNT_OFF);
    if (V > NPAD) V = NPAD;
    const unsigned long long* mask = (const unsigned long long*)(ws + MASK_OFF);
    const unsigned long long* diag = (const unsigned long long*)(ws + DIAG_OFF);
    unsigned long long* keepw = (unsigned long long*)(ws + KEEP_OFF);

    __shared__ unsigned int supp2[256];     // 128 u64 words as (lo,hi) u32 pairs
    __shared__ unsigned long long salive;
    __shared__ unsigned long long srownz[128];

    if (tid < 256) supp2[tid] = 0u;
    if (tid < 128) srownz[tid] = ((const unsigned long long*)(ws + ROWNZ_OFF))[tid];
    __syncthreads();

    int nch  = (V + 63) >> 6;
    int maxw = nch;

    unsigned long long A0[4], A1[4], B0[4], B1[4];
    #pragma unroll
    for (int s = 0; s < 4; ++s) { A0[s] = 0; A1[s] = 0; B0[s] = 0; B1[s] = 0; }
    unsigned long long dcur = 0;

    if (nch > 0) {                          // prefetch chunk 0
        unsigned long long rz = srownz[0];
        #pragma unroll
        for (int s = 0; s < 4; ++s) {
            int k = wv + (s << 4);
            bool need = ((rz >> k) & 1ull) != 0ull;
            A0[s] = (need && lane < maxw) ? mask[(size_t)k * NW + lane] : 0ull;
            A1[s] = (need && maxw > 64 && 64 + lane < maxw) ? mask[(size_t)k * NW + 64 + lane] : 0ull;
        }
        if (wv == 0) dcur = diag[lane];
    }

    for (int c = 0; c < nch; ++c) {
        if (c + 1 < nch) {                  // prefetch chunk c+1 (independent of resolve)
            unsigned long long rz = srownz[c + 1];
            int base = (c + 1) << 6;
            #pragma unroll
            for (int s = 0; s < 4; ++s) {
                int k = wv + (s << 4);
                bool need = ((rz >> k) & 1ull) != 0ull;
                B0[s] = (need && lane >= (c + 1) && lane < maxw) ? mask[(size_t)(base + k) * NW + lane] : 0ull;
                B1[s] = (need && maxw > 64 && 64 + lane < maxw) ? mask[(size_t)(base + k) * NW + 64 + lane] : 0ull;
            }
        }
        if (wv == 0) {                      // resolve chunk c
            unsigned long long aw = ((unsigned long long)supp2[2 * c + 1] << 32) | supp2[2 * c];
            int rem = V - (c << 6);
            unsigned long long tail = (rem >= 64) ? ~0ull : ((1ull << rem) - 1ull);
            unsigned long long alive = ~aw & tail;
            unsigned long long dnz = __ballot(dcur != 0ull);
            unsigned long long work = alive & dnz;
            while (work) {
                int k = __builtin_ctzll(work);
                work &= work - 1ull;
                unsigned long long dk = readlane64(dcur, k);
                alive &= ~dk;
                work  &= ~dk;
            }
            if (lane == 0) salive = alive;
            if (c + 1 < nch) dcur = diag[((c + 1) << 6) + lane];
        }
        __syncthreads();                    // salive + supp2(c) visible to all
        unsigned long long alive = salive;
        #pragma unroll
        for (int s = 0; s < 4; ++s) {
            int k = wv + (s << 4);
            if ((alive >> k) & 1ull) {
                if (A0[s]) {
                    atomicOr(&supp2[2 * lane],     (unsigned int)A0[s]);
                    atomicOr(&supp2[2 * lane + 1], (unsigned int)(A0[s] >> 32));
                }
                if (A1[s]) {
                    atomicOr(&supp2[2 * (64 + lane)],     (unsigned int)A1[s]);
                    atomicOr(&supp2[2 * (64 + lane) + 1], (unsigned int)(A1[s] >> 32));
                }
            }
        }
        __syncthreads();                    // supp2 updates done before next resolve
        #pragma unroll
        for (int s = 0; s < 4; ++s) { A0[s] = B0[s]; A1[s] = B1[s]; }
    }

    if (tid < 128)
        keepw[tid] = ~(((unsigned long long)supp2[2 * tid + 1] << 32) | supp2[2 * tid]);
}

// ---------------- write output: kept ranks get box values, everything else zero ----------------
__global__ __launch_bounds__(256) void output_kernel(const unsigned char* __restrict__ ws,
                                                     float* __restrict__ out) {
    int r = blockIdx.x * 256 + threadIdx.x;
    if (r >= NBOX) return;
    int V = *(const int*)(ws + COUNT_OFF);
    if (V > NPAD) V = NPAD;
    const unsigned long long* keepw = (const unsigned long long*)(ws + KEEP_OFF);
    bool keep = (r < V) && ((keepw[r >> 6] >> (r & 63)) & 1ull);
    float o0 = 0.f, o1 = 0.f, o2 = 0.f, o3 = 0.f, o4 = 0.f, o5 = 0.f;
    if (keep) {
        int idx = ((const int*)(ws + SIDX_OFF))[r];
        if (idx >= 0 && idx < NBOX) {
            o0 = ((const float*)(ws + UARR(0)))[idx];
            o1 = ((const float*)(ws + UARR(1)))[idx];
            o2 = ((const float*)(ws + UARR(2)))[idx];
            o3 = ((const float*)(ws + UARR(3)))[idx];
            o4 = ((const float*)(ws + UARR(4)))[idx];
            o5 = ((const float*)(ws + UARR(5)))[idx];
        }
    }
    out[r * 6 + 0] = o0;
    out[r * 6 + 1] = o1;
    out[r * 6 + 2] = o2;
    out[r * 6 + 3] = o3;
    out[r * 6 + 4] = o4;
    out[r * 6 + 5] = o5;
}

extern "C" void kernel_launch(void* const* d_in, const int* in_sizes, int n_in,
                              void* d_out, int out_size, void* d_ws, size_t ws_size,
                              hipStream_t stream) {
    const float* x       = (const float*)d_in[0];
    const float* anchors = (const float*)d_in[1];
    float* out           = (float*)d_out;
    unsigned char* ws    = (unsigned char*)d_ws;

    hipMemsetAsync(ws, 0, 0x8800, stream);         // zero count + rownz + rank
    decode_kernel<<<(NBOX + 255) / 256, 256, 0, stream>>>(x, anchors, ws);
    dim3 rgrid(NPAD / 256, NPAD / 256);
    rank_kernel<<<rgrid, 256, 0, stream>>>(ws);
    scatter_kernel<<<NPAD / 256, 256, 0, stream>>>(ws);
    dim3 mgrid(NW, NPAD / 256);
    mask_kernel<<<mgrid, 256, 0, stream>>>(ws);
    scan_kernel<<<1, 1024, 0, stream>>>(ws);
    output_kernel<<<(NBOX + 255) / 256, 256, 0, stream>>>(ws, out);
}

// Round 5
// 137.284 us; speedup vs baseline: 4.0734x; 1.1647x over previous
//
#include <hip/hip_runtime.h>
#include <stdint.h>

#define NBOX 8000
#define NPAD 8192
#define NW   128      // 64-bit words per mask row (stride)
#define LCAP 16       // per-row sparse list capacity (u16 entries)
#define VLIM 4224     // list path valid while V <= VLIM (V~4000 for this input)

// ---- workspace layout (bytes) ----
#define COUNT_OFF 0
#define RANK_OFF  0x800                      // 8192 * 4 (memset 0)
#define VKEYS_OFF 0x9000                     // 8192 * 8
#define U_OFF     0x20000                    // 6 unsorted arrays
#define UARR(i)   (U_OFF + (size_t)(i) * NPAD * 4)   // bx,by,bw,bh,conf,cls
#define SIDX_OFF  0x50000                    // int[8192]
#define SARR(i)   (0x58000 + (size_t)(i) * NPAD * 4) // x1,y1,x2,y2,area,cls
#define KEEP_OFF  0x98000                    // 128 * 8
#define CNT_OFF   0x99000                    // 4352 * 4 (memset 0)
#define MASK_OFF  (size_t)0xA0000            // rows < V; when V<=VLIM only rows<4224 used
#define LIST_OFF  (size_t)0x4C0000           // 4224 * 16 * 2B (only used when V<=VLIM)

__device__ __forceinline__ float sigmoidf_(float x) {
    return 1.0f / (1.0f + expf(-x));
}

__device__ __forceinline__ unsigned long long readlane64(unsigned long long v, int l) {
    unsigned int lo = (unsigned int)__builtin_amdgcn_readlane((int)(unsigned int)(v & 0xffffffffull), l);
    unsigned int hi = (unsigned int)__builtin_amdgcn_readlane((int)(unsigned int)(v >> 32), l);
    return ((unsigned long long)hi << 32) | (unsigned long long)lo;
}

__device__ __forceinline__ unsigned int get16(const ulonglong2& a, const ulonglong2& b, int t) {
    unsigned long long src;
    if (t < 8) src = (t < 4) ? a.x : a.y;
    else       src = (t < 12) ? b.x : b.y;
    return (unsigned int)((src >> ((t & 3) << 4)) & 0xFFFFull);
}

// ---------------- decode: 1 wave/block, wave-aggregated key compaction ----------------
__global__ __launch_bounds__(64) void decode_kernel(const float* __restrict__ x,
                                                    const float* __restrict__ anchors,
                                                    unsigned char* __restrict__ ws) {
    int n = blockIdx.x * 64 + threadIdx.x;          // 125*64 = 8000 exactly
    int a   = n / 1600;
    int pos = n - a * 1600;
    int gy  = pos / 40;
    int gx  = pos - gy * 40;
    const float* p = x + (size_t)a * 25 * 1600 + pos;

    float tx   = sigmoidf_(p[0]);
    float ty   = sigmoidf_(p[1600]);
    float tw   = p[2 * 1600];
    float th   = p[3 * 1600];
    float conf = sigmoidf_(p[4 * 1600]);

    float best = -1.0f; int bi = 0;
    #pragma unroll
    for (int c = 0; c < 20; ++c) {                  // first-max wins, matches jnp.argmax
        float v = sigmoidf_(p[(5 + c) * 1600]);
        if (v > best) { best = v; bi = c; }
    }

    float aw = anchors[a * 2 + 0];
    float ah = anchors[a * 2 + 1];
    float bx = (tx + (float)gx) * 8.0f;
    float by = (ty + (float)gy) * 8.0f;
    float bw = expf(tw) * aw * 8.0f;
    float bh = expf(th) * ah * 8.0f;

    ((float*)(ws + UARR(0)))[n] = bx;
    ((float*)(ws + UARR(1)))[n] = by;
    ((float*)(ws + UARR(2)))[n] = bw;
    ((float*)(ws + UARR(3)))[n] = bh;
    ((float*)(ws + UARR(4)))[n] = conf;
    ((float*)(ws + UARR(5)))[n] = (float)bi;

    bool valid = conf > 0.5f;                       // strict >, matches ref
    unsigned long long bal = __ballot(valid);
    if (bal) {
        int lead = __builtin_ctzll(bal);
        unsigned int base = 0;
        if ((int)threadIdx.x == lead)
            base = atomicAdd((unsigned int*)(ws + COUNT_OFF), (unsigned int)__popcll(bal));
        base = (unsigned int)__shfl((int)base, lead, 64);
        if (valid) {
            unsigned int cb = __float_as_uint(conf);   // conf in (0,1): bits monotonic
            unsigned long long key = ((unsigned long long)cb << 32) | (unsigned long long)(8191 - n);
            unsigned int slot = base + (unsigned int)__popcll(bal & ((1ull << threadIdx.x) - 1ull));
            ((unsigned long long*)(ws + VKEYS_OFF))[slot] = key;
        }
    }
}

// ---------------- 2D brute-force rank: rank[i] += #{keys in j-tile greater} ----------------
__global__ __launch_bounds__(256) void rank_kernel(unsigned char* __restrict__ ws) {
    __shared__ unsigned long long tile[256];
    int V = *(const int*)(ws + COUNT_OFF);
    if (V > NPAD) V = NPAD;
    int i0 = blockIdx.y << 8;
    int j0 = blockIdx.x << 8;
    if (i0 >= V || j0 >= V) return;
    const unsigned long long* vk = (const unsigned long long*)(ws + VKEYS_OFF);
    int i = i0 + threadIdx.x;
    unsigned long long ki = (i < V) ? vk[i] : ~0ull;
    int j = j0 + threadIdx.x;
    tile[threadIdx.x] = (j < V) ? vk[j] : 0ull;
    __syncthreads();
    int cnt = 0;
    #pragma unroll 8
    for (int jj = 0; jj < 256; ++jj) cnt += (tile[jj] > ki) ? 1 : 0;
    if (i < V && cnt) atomicAdd((int*)(ws + RANK_OFF) + i, cnt);
}

// ---------------- scatter by rank + compute sorted geometry ----------------
__global__ __launch_bounds__(256) void scatter_kernel(unsigned char* __restrict__ ws) {
#pragma clang fp contract(off)
    int i = blockIdx.x * 256 + threadIdx.x;
    if (i >= NPAD) return;
    int V = *(const int*)(ws + COUNT_OFF);
    if (V > NPAD) V = NPAD;
    float* sx1 = (float*)(ws + SARR(0));
    float* sy1 = (float*)(ws + SARR(1));
    float* sx2 = (float*)(ws + SARR(2));
    float* sy2 = (float*)(ws + SARR(3));
    float* sar = (float*)(ws + SARR(4));
    float* scl = (float*)(ws + SARR(5));
    if (i < V) {
        int r = ((const int*)(ws + RANK_OFF))[i];
        unsigned long long key = ((const unsigned long long*)(ws + VKEYS_OFF))[i];
        int idx = 8191 - (int)(key & 0x1FFFull);
        ((int*)(ws + SIDX_OFF))[r] = idx;
        float cx = ((float*)(ws + UARR(0)))[idx];
        float cy = ((float*)(ws + UARR(1)))[idx];
        float w  = ((float*)(ws + UARR(2)))[idx];
        float h  = ((float*)(ws + UARR(3)))[idx];
        float x1 = cx - w / 2.0f;
        float y1 = cy - h / 2.0f;
        float x2 = cx + w / 2.0f;
        float y2 = cy + h / 2.0f;
        sx1[r] = x1; sy1[r] = y1; sx2[r] = x2; sy2[r] = y2;
        sar[r] = fabsf((x2 - x1) * (y2 - y1));   // ref: recomputed from corners
        scl[r] = ((float*)(ws + UARR(5)))[idx];
    } else {
        int r = i;
        ((int*)(ws + SIDX_OFF))[r] = -1;
        sx1[r] = 0.f; sy1[r] = 0.f; sx2[r] = 0.f; sy2[r] = 0.f;
        sar[r] = 0.f; scl[r] = -1.0f;
    }
}

// ---------------- suppression bitmask + sparse per-row column lists ----------------
__global__ __launch_bounds__(256) void mask_kernel(unsigned char* __restrict__ ws) {
#pragma clang fp contract(off)
    int V = *(int*)(ws + COUNT_OFF);
    if (V > NPAD) V = NPAD;
    int i0 = blockIdx.y * 256;
    int w  = blockIdx.x;
    int j0 = w * 64;
    if (i0 >= V) return;
    if (j0 >= V) return;
    if (j0 + 64 <= i0) return;                     // strictly sub-diagonal: all zero
    int i  = i0 + threadIdx.x;

    const float* sx1 = (const float*)(ws + SARR(0));
    const float* sy1 = (const float*)(ws + SARR(1));
    const float* sx2 = (const float*)(ws + SARR(2));
    const float* sy2 = (const float*)(ws + SARR(3));
    const float* sar = (const float*)(ws + SARR(4));
    const float* scl = (const float*)(ws + SARR(5));

    __shared__ float cx1[64], cy1[64], cx2[64], cy2[64], car[64], ccl[64];
    if (threadIdx.x < 64) {
        int j = j0 + threadIdx.x;
        cx1[threadIdx.x] = sx1[j]; cy1[threadIdx.x] = sy1[j];
        cx2[threadIdx.x] = sx2[j]; cy2[threadIdx.x] = sy2[j];
        car[threadIdx.x] = sar[j]; ccl[threadIdx.x] = scl[j];
    }
    __syncthreads();
    if (i >= V) return;

    unsigned long long word = 0;
    if (j0 + 64 > i + 1) {
        float x1i = sx1[i], y1i = sy1[i], x2i = sx2[i], y2i = sy2[i];
        float ai = sar[i], ci = scl[i];
        for (int jj = 0; jj < 64; ++jj) {
            int j = j0 + jj;
            if (j <= i || j >= V) continue;
            if (ccl[jj] != ci) continue;
            float iw = fminf(x2i, cx2[jj]) - fmaxf(x1i, cx1[jj]);
            iw = fmaxf(iw, 0.0f);
            float ih = fminf(y2i, cy2[jj]) - fmaxf(y1i, cy1[jj]);
            ih = fmaxf(ih, 0.0f);
            float inter = iw * ih;
            float denom = ai + car[jj] - inter + 1e-6f;   // ((ai+aj)-inter)+eps, L-to-R
            if (inter / denom >= 0.5f) word |= (1ull << jj);
        }
    }
    ((unsigned long long*)(ws + MASK_OFF))[(size_t)i * NW + w] = word;

    if (word && V <= VLIM) {                       // sparse list emission (i < V <= VLIM)
        int pc = __popcll(word);
        unsigned int b = atomicAdd((unsigned int*)(ws + CNT_OFF) + i, (unsigned int)pc);
        unsigned long long t = word;
        unsigned int o = 0;
        while (t) {
            int bit = __builtin_ctzll(t);
            t &= t - 1ull;
            unsigned int slot = b + o; ++o;
            if (slot < LCAP)
                ((unsigned short*)(ws + LIST_OFF))[(size_t)i * LCAP + slot] =
                    (unsigned short)(j0 + bit);
        }
    }
}

// ---------------- greedy scan: ONE wave, zero barriers, sparse lists ----------------
// Suppression bitmap in LDS (256 u32). Per 64-row chunk: read supp word, build
// in-chunk suppression words from register-resident prefetched lists, resolve
// greedily on the scalar unit (ctz loop), then alive lanes scatter their list
// entries via LDS atomicOr. Rows with cnt > LCAP (rare) use their bitmask row.
__global__ __launch_bounds__(64, 1) void scan_kernel(unsigned char* __restrict__ ws) {
    int lane = threadIdx.x;
    int V = *(const int*)(ws + COUNT_OFF);
    if (V > NPAD) V = NPAD;
    const unsigned long long* mask = (const unsigned long long*)(ws + MASK_OFF);
    const unsigned int*  cnt  = (const unsigned int*)(ws + CNT_OFF);
    const ulonglong2*    lst  = (const ulonglong2*)(ws + LIST_OFF);
    unsigned long long*  keepw = (unsigned long long*)(ws + KEEP_OFF);

    __shared__ unsigned int supp2[256];            // 8192-bit suppression bitmap
    #pragma unroll
    for (int k = 0; k < 4; ++k) supp2[lane * 4 + k] = 0u;

    int nch  = (V + 63) >> 6;
    int maxw = nch;
    bool useL = (V <= VLIM);

    unsigned int cA = 0; ulonglong2 lA0 = {0,0}, lA1 = {0,0};
    {
        int row = lane;
        if (useL && row < V) {
            cA  = cnt[row];
            lA0 = lst[(size_t)row * 2];
            lA1 = lst[(size_t)row * 2 + 1];
        }
    }

    for (int c = 0; c < nch; ++c) {
        int base = c << 6;
        int row  = base + lane;

        // prefetch chunk c+1
        unsigned int cB = 0; ulonglong2 lB0 = {0,0}, lB1 = {0,0};
        {
            int row2 = base + 64 + lane;
            if (useL && c + 1 < nch && row2 < V) {
                cB  = cnt[row2];
                lB0 = lst[(size_t)row2 * 2];
                lB1 = lst[(size_t)row2 * 2 + 1];
            }
        }

        unsigned long long aw = ((unsigned long long)supp2[2 * c + 1] << 32) | supp2[2 * c];
        int rem = V - base;
        unsigned long long tail = (rem >= 64) ? ~0ull : ((1ull << rem) - 1ull);
        unsigned long long alive = ~aw & tail;

        // in-chunk suppression word for my row
        unsigned long long inw = 0;
        if (useL) {
            unsigned int cc = (cA < LCAP) ? cA : LCAP;
            for (int t = 0; t < LCAP; ++t) {
                bool act = ((unsigned int)t < cc);
                if (!__any(act)) break;
                if (act) {
                    unsigned int j = get16(lA0, lA1, t);
                    unsigned int d = j - (unsigned int)base;
                    if (d < 64u) inw |= (1ull << d);
                }
            }
            if (cA > LCAP && row < V) inw = mask[(size_t)row * NW + c];  // overflow: exact word
        } else {
            if (row < V) inw = mask[(size_t)row * NW + c];
        }

        // greedy resolve on the scalar unit
        unsigned long long dnz = __ballot(inw != 0ull);
        unsigned long long work = alive & dnz;
        while (work) {
            int k = __builtin_ctzll(work);
            work &= work - 1ull;
            unsigned long long dk = readlane64(inw, k);
            alive &= ~dk;
            work  &= ~dk;
        }

        // scatter suppressions of alive rows
        bool am = ((alive >> lane) & 1ull) && (row < V);
        if (useL) {
            if (am && cA <= LCAP) {
                for (unsigned int t = 0; t < cA; ++t) {
                    unsigned int j = get16(lA0, lA1, (int)t);
                    atomicOr(&supp2[j >> 5], 1u << (j & 31));
                }
            }
            unsigned long long ofl = __ballot(am && cA > LCAP);    // rare
            while (ofl) {
                int k = __builtin_ctzll(ofl);
                ofl &= ofl - 1ull;
                size_t rb = (size_t)(base + k) * NW;
                for (int ww = c + lane; ww < maxw; ww += 64) {
                    unsigned long long m = mask[rb + ww];
                    if (m) {
                        atomicOr(&supp2[2 * ww],     (unsigned int)m);
                        atomicOr(&supp2[2 * ww + 1], (unsigned int)(m >> 32));
                    }
                }
            }
        } else {
            unsigned long long av = __ballot(am);                  // full fallback
            while (av) {
                int k = __builtin_ctzll(av);
                av &= av - 1ull;
                size_t rb = (size_t)(base + k) * NW;
                for (int ww = c + lane; ww < maxw; ww += 64) {
                    unsigned long long m = mask[rb + ww];
                    if (m) {
                        atomicOr(&supp2[2 * ww],     (unsigned int)m);
                        atomicOr(&supp2[2 * ww + 1], (unsigned int)(m >> 32));
                    }
                }
            }
        }

        cA = cB; lA0 = lB0; lA1 = lB1;
    }

    keepw[lane] = ~(((unsigned long long)supp2[2 * lane + 1] << 32) | supp2[2 * lane]);
    keepw[64 + lane] = ~(((unsigned long long)supp2[2 * (64 + lane) + 1] << 32) | supp2[2 * (64 + lane)]);
}

// ---------------- write output ----------------
__global__ __launch_bounds__(256) void output_kernel(const unsigned char* __restrict__ ws,
                                                     float* __restrict__ out) {
    int r = blockIdx.x * 256 + threadIdx.x;
    if (r >= NBOX) return;
    int V = *(const int*)(ws + COUNT_OFF);
    if (V > NPAD) V = NPAD;
    const unsigned long long* keepw = (const unsigned long long*)(ws + KEEP_OFF);
    bool keep = (r < V) && ((keepw[r >> 6] >> (r & 63)) & 1ull);
    float o0 = 0.f, o1 = 0.f, o2 = 0.f, o3 = 0.f, o4 = 0.f, o5 = 0.f;
    if (keep) {
        int idx = ((const int*)(ws + SIDX_OFF))[r];
        if (idx >= 0 && idx < NBOX) {
            o0 = ((const float*)(ws + UARR(0)))[idx];
            o1 = ((const float*)(ws + UARR(1)))[idx];
            o2 = ((const float*)(ws + UARR(2)))[idx];
            o3 = ((const float*)(ws + UARR(3)))[idx];
            o4 = ((const float*)(ws + UARR(4)))[idx];
            o5 = ((const float*)(ws + UARR(5)))[idx];
        }
    }
    out[r * 6 + 0] = o0;
    out[r * 6 + 1] = o1;
    out[r * 6 + 2] = o2;
    out[r * 6 + 3] = o3;
    out[r * 6 + 4] = o4;
    out[r * 6 + 5] = o5;
}

extern "C" void kernel_launch(void* const* d_in, const int* in_sizes, int n_in,
                              void* d_out, int out_size, void* d_ws, size_t ws_size,
                              hipStream_t stream) {
    const float* x       = (const float*)d_in[0];
    const float* anchors = (const float*)d_in[1];
    float* out           = (float*)d_out;
    unsigned char* ws    = (unsigned char*)d_ws;

    hipMemsetAsync(ws, 0, 0x8800, stream);                 // count + rank
    hipMemsetAsync(ws + CNT_OFF, 0, 0x4400, stream);       // per-row list counts
    decode_kernel<<<125, 64, 0, stream>>>(x, anchors, ws);
    dim3 rgrid(NPAD / 256, NPAD / 256);
    rank_kernel<<<rgrid, 256, 0, stream>>>(ws);
    scatter_kernel<<<NPAD / 256, 256, 0, stream>>>(ws);
    dim3 mgrid(NW, NPAD / 256);
    mask_kernel<<<mgrid, 256, 0, stream>>>(ws);
    scan_kernel<<<1, 64, 0, stream>>>(ws);
    output_kernel<<<(NBOX + 255) / 256, 256, 0, stream>>>(ws, out);
}